// Round 1
// baseline (718.888 us; speedup 1.0000x reference)
//
#include <hip/hip_runtime.h>

// CrossAttentionDecoder: B=1024, n_tok=16, n_lat=128, d=512, h=8, dh=64
// cast(w,x,l)->bf16 -> Q proj -> fused KV proj (K row-major, V transposed)
// -> masked attn -> O proj.
// This round: KV GEMM rewritten as 256x256/BK=32, 8-wave, 4-slot LDS ring,
// lead-3 global_load_lds prefetch + counted vmcnt(8) + setprio + XOR swizzle.

typedef __bf16 bf16;
typedef __attribute__((ext_vector_type(8))) __bf16 bf16x8;
typedef __attribute__((ext_vector_type(4))) __bf16 bf16x4;
typedef __attribute__((ext_vector_type(4))) float  float4v;

#define MFMA16(a, b, c) __builtin_amdgcn_mfma_f32_16x16x32_bf16((a), (b), (c), 0, 0, 0)

// global -> LDS direct 16B copy: per-lane global addr, wave-uniform LDS base,
// lane i lands at ldsbase + i*16 (m97/m104 semantics).
__device__ __forceinline__ void gl2lds16(const bf16* g, bf16* l) {
    __builtin_amdgcn_global_load_lds(
        (const __attribute__((address_space(1))) void*)g,
        (__attribute__((address_space(3))) void*)l, 16, 0, 0);
}

// ---------------------------------------------------------------------------
__global__ __launch_bounds__(256) void cast_f32_bf16(const float* __restrict__ src,
                                                     bf16* __restrict__ dst, int n4) {
    const int stride = gridDim.x * 256;
    for (int i = blockIdx.x * 256 + threadIdx.x; i < n4; i += stride) {
        float4v f = ((const float4v*)src)[i];
        ((bf16x4*)dst)[i] = bf16x4{(bf16)f.x, (bf16)f.y, (bf16)f.z, (bf16)f.w};
    }
}

__global__ __launch_bounds__(256) void cast_weights(const float* __restrict__ Wq,
                                                    const float* __restrict__ Wk,
                                                    const float* __restrict__ Wv,
                                                    const float* __restrict__ Wo,
                                                    bf16* __restrict__ Wq_b,
                                                    bf16* __restrict__ Wkv_b,
                                                    bf16* __restrict__ Wo_b) {
    const int i = blockIdx.x * 256 + threadIdx.x;  // float4 units
    const int w = i >> 16;
    const int j = i & 65535;
    const float* src = (w == 0) ? Wq : (w == 1) ? Wk : (w == 2) ? Wv : Wo;
    bf16x4* dst = (w == 0) ? (bf16x4*)Wq_b
                : (w == 1) ? (bf16x4*)Wkv_b
                : (w == 2) ? ((bf16x4*)Wkv_b) + 65536
                           : (bf16x4*)Wo_b;
    float4v f = ((const float4v*)src)[j];
    dst[j] = bf16x4{(bf16)f.x, (bf16)f.y, (bf16)f.z, (bf16)f.w};
}

// ---------------------------------------------------------------------------
// Small GEMMs (Q and O projections): C[M x N] = A[M x 512] @ W[N x 512]^T,
// bf16, 128x128 tile, BK=32 (m97 structure — adequate at these sizes).
// MODE 0: bf16 row-major out. MODE 2: fp32 + bias.
template <int MODE>
__global__ __launch_bounds__(256) void gemm_bt(const bf16* __restrict__ A,
                                               const bf16* __restrict__ W,
                                               void* __restrict__ C0,
                                               const float* __restrict__ bias,
                                               int nT, int mPerXcd) {
    __shared__ alignas(16) bf16 Asl[128 * 32];
    __shared__ alignas(16) bf16 Bsl[128 * 32];

    const int bid = blockIdx.x;
    const int xcd = bid & 7;
    const int s   = bid >> 3;
    const int mt  = xcd * mPerXcd + s / nT;
    const int nt  = s % nT;
    const int m0  = mt * 128;
    const int n0  = nt * 128;

    const int tid  = threadIdx.x;
    const int wave = tid >> 6;
    const int lane = tid & 63;
    const int mi   = lane & 15;
    const int quad = lane >> 4;
    const int qrow = (wave >> 1) * 64;
    const int qcol = (wave & 1) * 64;

    const int srow = wave * 16 + (lane >> 2);
    const int scol = (lane & 3) * 8;

    float4v acc[4][4] = {};

    for (int kt = 0; kt < 16; ++kt) {
        const int k0 = kt * 32;
#pragma unroll
        for (int r = 0; r < 2; ++r) {
            gl2lds16(A + (size_t)(m0 + srow + r * 64) * 512 + k0 + scol,
                     &Asl[wave * 512 + r * 2048]);
            gl2lds16(W + (size_t)(n0 + srow + r * 64) * 512 + k0 + scol,
                     &Bsl[wave * 512 + r * 2048]);
        }
        __syncthreads();

        bf16x8 af[4], bfr[4];
#pragma unroll
        for (int i = 0; i < 4; ++i)
            af[i] = *(const bf16x8*)&Asl[(qrow + i * 16 + mi) * 32 + quad * 8];
#pragma unroll
        for (int j = 0; j < 4; ++j)
            bfr[j] = *(const bf16x8*)&Bsl[(qcol + j * 16 + mi) * 32 + quad * 8];
#pragma unroll
        for (int i = 0; i < 4; ++i)
#pragma unroll
            for (int j = 0; j < 4; ++j)
                acc[i][j] = MFMA16(af[i], bfr[j], acc[i][j]);
        __syncthreads();
    }

#pragma unroll
    for (int i = 0; i < 4; ++i) {
#pragma unroll
        for (int j = 0; j < 4; ++j) {
            const int row = m0 + qrow + i * 16 + quad * 4;
            const int col = n0 + qcol + j * 16 + mi;
#pragma unroll
            for (int r = 0; r < 4; ++r) {
                float v = acc[i][j][r];
                if (MODE == 2)
                    ((float*)C0)[(size_t)(row + r) * 512 + col] = v + bias[col];
                else
                    ((bf16*)C0)[(size_t)(row + r) * 512 + col] = (bf16)v;
            }
        }
    }
}

// ---------------------------------------------------------------------------
// KV projection GEMM, phased schedule.
//   C[131072 x 1024] = lb[131072 x 512] @ Wkv[1024 x 512]^T
//   BM=BN=256, BK=32, 512 thr = 8 waves (2m x 4n), per-wave output 128x64.
//   LDS: 4-slot ring x (A 16KB + B 16KB) = 128 KiB -> 1 block/CU.
//   Prefetch: during tile t, stage tile t+3 into slot (t+3)&3 = (t-1)&3 —
//   that slot's last reader finished before the barrier ending tile t-1,
//   and stage issues sit after that barrier in program order => race-free.
//   End-of-tile s_waitcnt vmcnt(8): leaves tiles t+2,t+3 (4 loads/wave each)
//   in flight, guarantees t+1 resident. Never drains to 0 until the tail.
//   Swizzle (rule #21, both-sides): LDS[row][u16B] = global[row][u ^ (row&3)]
//   via pre-swizzled global source; ds_read uses unit (quad ^ (mi&3)) so the
//   lane receives global k-slice quad*8..+8 — unswizzled 8-way conflict -> ~2.
//   nt<2 -> K row-major (131072,512); nt>=2 -> Vt[b][dd][lat] (b = mt*2+wm).
__global__ __launch_bounds__(512, 2) void gemm_kv(const bf16* __restrict__ A,
                                                  const bf16* __restrict__ W,
                                                  bf16* __restrict__ Kout,
                                                  bf16* __restrict__ Vt) {
    __shared__ alignas(16) bf16 As[4][256 * 32];
    __shared__ alignas(16) bf16 Bs[4][256 * 32];

    const int bid = blockIdx.x;
    const int xcd = bid & 7;
    const int s   = bid >> 3;
    const int mt  = xcd * 64 + (s >> 2);   // 512 m-tiles, nT = 4
    const int nt  = s & 3;
    const int m0  = mt * 256;
    const int n0  = nt * 256;

    const int tid  = threadIdx.x;
    const int wv   = tid >> 6;   // 0..7
    const int lane = tid & 63;
    const int wm   = wv >> 2;    // 0..1 : 128-row half
    const int wn   = wv & 3;     // 0..3 : 64-col slice
    const int mi   = lane & 15;
    const int quad = lane >> 4;

    // staging constants: lane i -> LDS row srow, 16B-unit (i&3); source column
    // pre-swizzled so LDS[row][u] = global[row][u ^ (row&3)].
    const int srow  = lane >> 2;                    // 0..15 within a 16-row group
    const int sunit = (lane & 3) ^ (srow & 3);      // global 16B unit
    const bf16* gA = A + (size_t)(m0 + wv * 32 + srow) * 512 + sunit * 8;
    const bf16* gB = W + (size_t)(n0 + wv * 32 + srow) * 512 + sunit * 8;
    const int ldsOff0 = (wv * 32) * 32;             // elems: rows wv*32 .. +15
    const int ldsOff1 = ldsOff0 + 16 * 32;          // rows +16 .. +31

    // fragment-read constants: row-dependent unit XOR undoes the staging swizzle
    const int funit = (quad ^ (mi & 3)) * 8;        // elems within 32-elem row
    const int arow0 = wm * 128 + mi;                // + mh*64 + ii*16
    const int brow0 = wn * 64 + mi;                 // + j*16

    float4v acc[8][4] = {};

#define KV_STAGE(t, ph)                                                        \
    do {                                                                       \
        const int _sl = (t) & 3;                                               \
        gl2lds16(gA + (ph) * (16 * 512) + (t) * 32,                            \
                 &As[_sl][(ph) ? ldsOff1 : ldsOff0]);                          \
        gl2lds16(gB + (ph) * (16 * 512) + (t) * 32,                            \
                 &Bs[_sl][(ph) ? ldsOff1 : ldsOff0]);                          \
    } while (0)

    // prologue: tiles 0,1,2 (12 loads/wave); wait tile 0 (8 = tiles 1,2 in flight)
#pragma unroll
    for (int t = 0; t < 3; ++t) { KV_STAGE(t, 0); KV_STAGE(t, 1); }
    asm volatile("s_waitcnt vmcnt(8)" ::: "memory");
    asm volatile("s_barrier" ::: "memory");

    bf16x8 bfr[4];
#pragma unroll
    for (int t = 0; t < 16; ++t) {
        const int sl = t & 3;
#pragma unroll
        for (int mh = 0; mh < 2; ++mh) {
            // ds-load this phase's fragments (B once per tile, reused in phase 1)
            bf16x8 af[4];
#pragma unroll
            for (int ii = 0; ii < 4; ++ii)
                af[ii] = *(const bf16x8*)
                    &As[sl][(arow0 + mh * 64 + ii * 16) * 32 + funit];
            if (mh == 0) {
#pragma unroll
                for (int j = 0; j < 4; ++j)
                    bfr[j] = *(const bf16x8*)&Bs[sl][(brow0 + j * 16) * 32 + funit];
            }
            // stage half of tile t+3 (2 loads/wave/phase)
            if (t < 13) KV_STAGE(t + 3, mh);

            asm volatile("s_barrier" ::: "memory");
            asm volatile("s_waitcnt lgkmcnt(0)" ::: "memory");
            __builtin_amdgcn_s_setprio(1);
#pragma unroll
            for (int ii = 0; ii < 4; ++ii)
#pragma unroll
                for (int j = 0; j < 4; ++j)
                    acc[mh * 4 + ii][j] = MFMA16(af[ii], bfr[j], acc[mh * 4 + ii][j]);
            __builtin_amdgcn_s_setprio(0);

            if (mh == 1) {
                // counted wait: t+1 resident; tiles t+2,t+3 stay in flight
                if (t <= 12)      asm volatile("s_waitcnt vmcnt(8)" ::: "memory");
                else if (t == 13) asm volatile("s_waitcnt vmcnt(4)" ::: "memory");
                else if (t == 14) asm volatile("s_waitcnt vmcnt(0)" ::: "memory");
            }
            asm volatile("s_barrier" ::: "memory");
        }
    }
#undef KV_STAGE

    // epilogue: C row = m0 + wm*128 + i*16 + quad*4 + r ; col = n0 + wn*64 + j*16 + mi
    if (nt < 2) {
#pragma unroll
        for (int i = 0; i < 8; ++i) {
            const int row = m0 + wm * 128 + i * 16 + quad * 4;
#pragma unroll
            for (int j = 0; j < 4; ++j) {
                const int col = n0 + wn * 64 + j * 16 + mi;
#pragma unroll
                for (int r = 0; r < 4; ++r)
                    Kout[(size_t)(row + r) * 512 + col] = (bf16)acc[i][j][r];
            }
        }
    } else {
        const size_t b = (size_t)mt * 2 + wm;   // BM=256 = 2 batches
#pragma unroll
        for (int i = 0; i < 8; ++i) {
            const int lat0 = i * 16 + quad * 4;
#pragma unroll
            for (int j = 0; j < 4; ++j) {
                const int dd = (n0 - 512) + wn * 64 + j * 16 + mi;
                bf16x4 o = {(bf16)acc[i][j][0], (bf16)acc[i][j][1],
                            (bf16)acc[i][j][2], (bf16)acc[i][j][3]};
                *(bf16x4*)(Vt + (b * 512 + dd) * 128 + lat0) = o;
            }
        }
    }
}

// ---------------------------------------------------------------------------
// Attention: 4 waves/block, wave w handles bh = blockIdx.x*4 + w.
// K row-major (131072, 512); Vt transposed (1024, 512, 128): all MFMA operands
// are contiguous 16B loads. Mask-aware: only ntiles = (b%128)/16+1 tiles live.
__global__ __launch_bounds__(256) void attn_kernel(const bf16* __restrict__ Q,
                                                   const bf16* __restrict__ K,
                                                   const bf16* __restrict__ Vt,
                                                   bf16* __restrict__ O) {
    __shared__ alignas(16) bf16 Plds[4][16 * 136];   // per-wave P tile, padded

    const int w      = threadIdx.x >> 6;
    const int bh     = blockIdx.x * 4 + w;
    const int b      = bh >> 3;
    const int h      = bh & 7;
    const int rowb   = b & 127;                   // allowed latents: j <= rowb
    const int ntiles = (rowb >> 4) + 1;           // active 16-latent tiles
    const int nkt    = (ntiles + 1) >> 1;         // active 32-latent PV k-steps
    const int lane   = threadIdx.x & 63;
    const int mi     = lane & 15;
    const int quad   = lane >> 4;

    // Q fragments: A[m=tok=mi][k=quad*8+j]
    const bf16* qbase = Q + (size_t)(b * 16 + mi) * 512 + h * 64 + quad * 8;
    const bf16x8 aq0 = *(const bf16x8*)(qbase);
    const bf16x8 aq1 = *(const bf16x8*)(qbase + 32);

    // scores: B[k=dh][n=lat] from K rows (BT form)
    float4v sc[8];
    const bf16* kbase = K + (size_t)(b * 128 + mi) * 512 + h * 64 + quad * 8;
#pragma unroll
    for (int jt = 0; jt < 8; ++jt) {
        if (jt < ntiles) {
            const bf16* kb = kbase + (size_t)jt * 16 * 512;
            bf16x8 bk0 = *(const bf16x8*)(kb);
            bf16x8 bk1 = *(const bf16x8*)(kb + 32);
            float4v a = {};
            a = MFMA16(aq0, bk0, a);
            a = MFMA16(aq1, bk1, a);
            sc[jt] = a;
        }
    }

    // mask boundary tile + scale (col = jt*16 + mi)
#pragma unroll
    for (int jt = 0; jt < 8; ++jt) {
        if (jt < ntiles) {
            const bool masked = (jt * 16 + mi) > rowb;
#pragma unroll
            for (int r = 0; r < 4; ++r)
                sc[jt][r] = masked ? -1e30f : sc[jt][r] * 0.125f;
        }
    }

    // softmax per token row (row = quad*4+r), reduce across the 16 mi lanes
#pragma unroll
    for (int r = 0; r < 4; ++r) {
        float mx = sc[0][r];
#pragma unroll
        for (int jt = 1; jt < 8; ++jt)
            if (jt < ntiles) mx = fmaxf(mx, sc[jt][r]);
#pragma unroll
        for (int off = 1; off < 16; off <<= 1) mx = fmaxf(mx, __shfl_xor(mx, off, 64));
        float s = 0.f;
#pragma unroll
        for (int jt = 0; jt < 8; ++jt) {
            if (jt < ntiles) {
                float p = __expf(sc[jt][r] - mx);
                sc[jt][r] = p;
                s += p;
            }
        }
#pragma unroll
        for (int off = 1; off < 16; off <<= 1) s += __shfl_xor(s, off, 64);
        const float inv = 1.f / s;
#pragma unroll
        for (int jt = 0; jt < 8; ++jt) {
            if (jt < 2 * nkt) {
                float p = (jt < ntiles) ? sc[jt][r] * inv : 0.f;
                Plds[w][(quad * 4 + r) * 136 + jt * 16 + mi] = (bf16)p;
            }
        }
    }
    __syncthreads();

    // out = P @ V: A[m=tok][k=lat] from Plds; B[k=lat][n=dd] from Vt rows.
    float4v ao[4] = {};
    const bf16* vb0 = Vt + ((size_t)b * 512 + h * 64) * 128;
#pragma unroll
    for (int ks = 0; ks < 4; ++ks) {
        if (ks < nkt) {
            bf16x8 ap = *(const bf16x8*)&Plds[w][mi * 136 + ks * 32 + quad * 8];
#pragma unroll
            for (int jt = 0; jt < 4; ++jt) {
                bf16x8 bv = *(const bf16x8*)(vb0 + (size_t)(jt * 16 + mi) * 128
                                             + ks * 32 + quad * 8);
                ao[jt] = MFMA16(ap, bv, ao[jt]);
            }
        }
    }

    // write merged-head output (16384, 512) bf16
#pragma unroll
    for (int jt = 0; jt < 4; ++jt)
#pragma unroll
        for (int r = 0; r < 4; ++r)
            O[(size_t)(b * 16 + quad * 4 + r) * 512 + h * 64 + jt * 16 + mi] =
                (bf16)ao[jt][r];
}

// ---------------------------------------------------------------------------
extern "C" void kernel_launch(void* const* d_in, const int* in_sizes, int n_in,
                              void* d_out, int out_size, void* d_ws, size_t ws_size,
                              hipStream_t stream) {
    const float* x  = (const float*)d_in[0];   // (16384, 512)
    const float* l  = (const float*)d_in[1];   // (131072, 512)
    const float* Wq = (const float*)d_in[2];
    const float* Wk = (const float*)d_in[3];
    const float* Wv = (const float*)d_in[4];
    const float* Wo = (const float*)d_in[5];
    const float* bo = (const float*)d_in[6];
    // d_in[7] = num_heads (8), hard-coded.

    char* ws = (char*)d_ws;
    size_t off = 0;
    bf16* Wq_b  = (bf16*)(ws + off); off += (size_t)512 * 512 * 2;
    bf16* Wo_b  = (bf16*)(ws + off); off += (size_t)512 * 512 * 2;
    bf16* Wkv_b = (bf16*)(ws + off); off += (size_t)1024 * 512 * 2;   // [Wk;Wv]
    bf16* xb    = (bf16*)(ws + off); off += (size_t)16384 * 512 * 2;
    bf16* lb    = (bf16*)(ws + off); off += (size_t)131072 * 512 * 2;
    bf16* Qb    = (bf16*)(ws + off); off += (size_t)16384 * 512 * 2;
    bf16* Kb    = (bf16*)(ws + off); off += (size_t)131072 * 512 * 2;
    bf16* Vtb   = (bf16*)(ws + off); off += (size_t)1024 * 512 * 128 * 2;
    bf16* AOb   = (bf16*)(ws + off);

    cast_weights<<<1024, 256, 0, stream>>>(Wq, Wk, Wv, Wo, Wq_b, Wkv_b, Wo_b);
    cast_f32_bf16<<<2048, 256, 0, stream>>>(x, xb, 16384 * 512 / 4);
    cast_f32_bf16<<<8192, 256, 0, stream>>>(l, lb, 131072 * 512 / 4);

    // Q: 128 m-tiles x 4 n-tiles (old 128^2 structure, small shape)
    gemm_bt<0><<<512, 256, 0, stream>>>(xb, Wq_b, Qb, nullptr, 4, 16);
    // KV: 512 m-tiles x 4 n-tiles of 256^2, phased schedule
    gemm_kv<<<2048, 512, 0, stream>>>(lb, Wkv_b, Kb, Vtb);

    attn_kernel<<<2048, 256, 0, stream>>>(Qb, Kb, Vtb, AOb);

    gemm_bt<2><<<512, 256, 0, stream>>>(AOb, Wo_b, d_out, bo, 4, 16);
}

// Round 2
// 683.287 us; speedup vs baseline: 1.0521x; 1.0521x over previous
//
#include <hip/hip_runtime.h>

// CrossAttentionDecoder: B=1024, n_tok=16, n_lat=128, d=512, h=8, dh=64
// cast(w,x,l)->bf16 -> Q proj -> fused KV proj (K row-major, V transposed)
// -> masked attn -> O proj.
// Round 2: KV GEMM keeps the 256x256/BK=32 4-slot ring, with
//  (a) corrected LDS swizzle: unit ^= (row>>1)&3  (covers all 8 bank-groups
//      per 16-lane quarter; previous row&3 XOR left a 2-way conflict), and
//  (b) LDS-staged coalesced epilogue (scattered per-fragment stores were
//      fully exposed at 1 block/CU).

typedef __bf16 bf16;
typedef __attribute__((ext_vector_type(8))) __bf16 bf16x8;
typedef __attribute__((ext_vector_type(4))) __bf16 bf16x4;
typedef __attribute__((ext_vector_type(4))) float  float4v;

#define MFMA16(a, b, c) __builtin_amdgcn_mfma_f32_16x16x32_bf16((a), (b), (c), 0, 0, 0)

// global -> LDS direct 16B copy: per-lane global addr, wave-uniform LDS base,
// lane i lands at ldsbase + i*16 (m97/m104 semantics).
__device__ __forceinline__ void gl2lds16(const bf16* g, bf16* l) {
    __builtin_amdgcn_global_load_lds(
        (const __attribute__((address_space(1))) void*)g,
        (__attribute__((address_space(3))) void*)l, 16, 0, 0);
}

// ---------------------------------------------------------------------------
__global__ __launch_bounds__(256) void cast_f32_bf16(const float* __restrict__ src,
                                                     bf16* __restrict__ dst, int n4) {
    const int stride = gridDim.x * 256;
    for (int i = blockIdx.x * 256 + threadIdx.x; i < n4; i += stride) {
        float4v f = ((const float4v*)src)[i];
        ((bf16x4*)dst)[i] = bf16x4{(bf16)f.x, (bf16)f.y, (bf16)f.z, (bf16)f.w};
    }
}

__global__ __launch_bounds__(256) void cast_weights(const float* __restrict__ Wq,
                                                    const float* __restrict__ Wk,
                                                    const float* __restrict__ Wv,
                                                    const float* __restrict__ Wo,
                                                    bf16* __restrict__ Wq_b,
                                                    bf16* __restrict__ Wkv_b,
                                                    bf16* __restrict__ Wo_b) {
    const int i = blockIdx.x * 256 + threadIdx.x;  // float4 units
    const int w = i >> 16;
    const int j = i & 65535;
    const float* src = (w == 0) ? Wq : (w == 1) ? Wk : (w == 2) ? Wv : Wo;
    bf16x4* dst = (w == 0) ? (bf16x4*)Wq_b
                : (w == 1) ? (bf16x4*)Wkv_b
                : (w == 2) ? ((bf16x4*)Wkv_b) + 65536
                           : (bf16x4*)Wo_b;
    float4v f = ((const float4v*)src)[j];
    dst[j] = bf16x4{(bf16)f.x, (bf16)f.y, (bf16)f.z, (bf16)f.w};
}

// ---------------------------------------------------------------------------
// Small GEMMs (Q and O projections): C[M x N] = A[M x 512] @ W[N x 512]^T,
// bf16, 128x128 tile, BK=32 (m97 structure — adequate at these sizes).
// MODE 0: bf16 row-major out. MODE 2: fp32 + bias.
template <int MODE>
__global__ __launch_bounds__(256) void gemm_bt(const bf16* __restrict__ A,
                                               const bf16* __restrict__ W,
                                               void* __restrict__ C0,
                                               const float* __restrict__ bias,
                                               int nT, int mPerXcd) {
    __shared__ alignas(16) bf16 Asl[128 * 32];
    __shared__ alignas(16) bf16 Bsl[128 * 32];

    const int bid = blockIdx.x;
    const int xcd = bid & 7;
    const int s   = bid >> 3;
    const int mt  = xcd * mPerXcd + s / nT;
    const int nt  = s % nT;
    const int m0  = mt * 128;
    const int n0  = nt * 128;

    const int tid  = threadIdx.x;
    const int wave = tid >> 6;
    const int lane = tid & 63;
    const int mi   = lane & 15;
    const int quad = lane >> 4;
    const int qrow = (wave >> 1) * 64;
    const int qcol = (wave & 1) * 64;

    const int srow = wave * 16 + (lane >> 2);
    const int scol = (lane & 3) * 8;

    float4v acc[4][4] = {};

    for (int kt = 0; kt < 16; ++kt) {
        const int k0 = kt * 32;
#pragma unroll
        for (int r = 0; r < 2; ++r) {
            gl2lds16(A + (size_t)(m0 + srow + r * 64) * 512 + k0 + scol,
                     &Asl[wave * 512 + r * 2048]);
            gl2lds16(W + (size_t)(n0 + srow + r * 64) * 512 + k0 + scol,
                     &Bsl[wave * 512 + r * 2048]);
        }
        __syncthreads();

        bf16x8 af[4], bfr[4];
#pragma unroll
        for (int i = 0; i < 4; ++i)
            af[i] = *(const bf16x8*)&Asl[(qrow + i * 16 + mi) * 32 + quad * 8];
#pragma unroll
        for (int j = 0; j < 4; ++j)
            bfr[j] = *(const bf16x8*)&Bsl[(qcol + j * 16 + mi) * 32 + quad * 8];
#pragma unroll
        for (int i = 0; i < 4; ++i)
#pragma unroll
            for (int j = 0; j < 4; ++j)
                acc[i][j] = MFMA16(af[i], bfr[j], acc[i][j]);
        __syncthreads();
    }

#pragma unroll
    for (int i = 0; i < 4; ++i) {
#pragma unroll
        for (int j = 0; j < 4; ++j) {
            const int row = m0 + qrow + i * 16 + quad * 4;
            const int col = n0 + qcol + j * 16 + mi;
#pragma unroll
            for (int r = 0; r < 4; ++r) {
                float v = acc[i][j][r];
                if (MODE == 2)
                    ((float*)C0)[(size_t)(row + r) * 512 + col] = v + bias[col];
                else
                    ((bf16*)C0)[(size_t)(row + r) * 512 + col] = (bf16)v;
            }
        }
    }
}

// ---------------------------------------------------------------------------
// KV projection GEMM, phased schedule.
//   C[131072 x 1024] = lb[131072 x 512] @ Wkv[1024 x 512]^T
//   BM=BN=256, BK=32, 512 thr = 8 waves (2m x 4n), per-wave output 128x64.
//   LDS: 4-slot ring x (A 16KB + B 16KB) = 128 KiB -> 1 block/CU.
//   Swizzle (both-sides): LDS[row][u] = global[row][u ^ ((row>>1)&3)], so a
//   b128 fragment read hits bank-group ((row&1)<<2)|(quad^((row>>1)&3)) —
//   all 8 groups per 16-lane quarter -> conflict-free.
//   vmcnt(8) once per tile (tiles t+2,t+3 stay in flight), drain at tail only.
//   Epilogue: acc -> LDS (ring is dead) -> fully coalesced 16B/lane stores.
//   nt<2 -> K row-major (131072,512); nt>=2 -> Vt[b][dd][lat] (b = mt*2+half).
__global__ __launch_bounds__(512, 2) void gemm_kv(const bf16* __restrict__ A,
                                                  const bf16* __restrict__ W,
                                                  bf16* __restrict__ Kout,
                                                  bf16* __restrict__ Vt) {
    __shared__ alignas(16) bf16 SH[2][4][256 * 32];   // [A/B][slot][tile]

    const int bid = blockIdx.x;
    const int xcd = bid & 7;
    const int s   = bid >> 3;
    const int mt  = xcd * 64 + (s >> 2);   // 512 m-tiles, nT = 4
    const int nt  = s & 3;
    const int m0  = mt * 256;
    const int n0  = nt * 256;

    const int tid  = threadIdx.x;
    const int wv   = tid >> 6;   // 0..7
    const int lane = tid & 63;
    const int wm   = wv >> 2;    // 0..1 : 128-row half
    const int wn   = wv & 3;     // 0..3 : 64-col slice
    const int mi   = lane & 15;
    const int quad = lane >> 4;

    // staging: lane i -> LDS row (i>>2), 16B-unit (i&3); source unit swizzled
    // so LDS[row][u] = global[row][u ^ ((row>>1)&3)]  (row bits 1-2 = srow 1-2).
    const int srow  = lane >> 2;                         // 0..15 in 16-row group
    const int sunit = (lane & 3) ^ ((lane >> 3) & 3);    // global 16B unit
    const bf16* gA = A + (size_t)(m0 + wv * 32 + srow) * 512 + sunit * 8;
    const bf16* gB = W + (size_t)(n0 + wv * 32 + srow) * 512 + sunit * 8;
    const int ldsOff0 = (wv * 32) * 32;                  // rows wv*32 .. +15
    const int ldsOff1 = ldsOff0 + 16 * 32;               // rows +16 .. +31

    // fragment reads: row ≡ mi (mod 16) -> un-swizzle with (mi>>1)&3
    const int funit = (quad ^ ((mi >> 1) & 3)) * 8;      // elems within row
    const int arow0 = wm * 128 + mi;                     // + mh*64 + ii*16
    const int brow0 = wn * 64 + mi;                      // + j*16

    float4v acc[8][4] = {};

#define KV_STAGE(t, ph)                                                        \
    do {                                                                       \
        const int _sl = (t) & 3;                                               \
        gl2lds16(gA + (ph) * (16 * 512) + (t) * 32,                            \
                 &SH[0][_sl][(ph) ? ldsOff1 : ldsOff0]);                       \
        gl2lds16(gB + (ph) * (16 * 512) + (t) * 32,                            \
                 &SH[1][_sl][(ph) ? ldsOff1 : ldsOff0]);                       \
    } while (0)

    // prologue: tiles 0,1,2 (12 loads/wave); wait tile 0 (8 = tiles 1,2 in flight)
#pragma unroll
    for (int t = 0; t < 3; ++t) { KV_STAGE(t, 0); KV_STAGE(t, 1); }
    asm volatile("s_waitcnt vmcnt(8)" ::: "memory");
    asm volatile("s_barrier" ::: "memory");

    bf16x8 bfr[4];
#pragma unroll
    for (int t = 0; t < 16; ++t) {
        const int sl = t & 3;
#pragma unroll
        for (int mh = 0; mh < 2; ++mh) {
            bf16x8 af[4];
#pragma unroll
            for (int ii = 0; ii < 4; ++ii)
                af[ii] = *(const bf16x8*)
                    &SH[0][sl][(arow0 + mh * 64 + ii * 16) * 32 + funit];
            if (mh == 0) {
#pragma unroll
                for (int j = 0; j < 4; ++j)
                    bfr[j] = *(const bf16x8*)
                        &SH[1][sl][(brow0 + j * 16) * 32 + funit];
            }
            if (t < 13) KV_STAGE(t + 3, mh);   // stage half of tile t+3

            asm volatile("s_barrier" ::: "memory");
            asm volatile("s_waitcnt lgkmcnt(0)" ::: "memory");
            __builtin_amdgcn_s_setprio(1);
#pragma unroll
            for (int ii = 0; ii < 4; ++ii)
#pragma unroll
                for (int j = 0; j < 4; ++j)
                    acc[mh * 4 + ii][j] = MFMA16(af[ii], bfr[j], acc[mh * 4 + ii][j]);
            __builtin_amdgcn_s_setprio(0);

            if (mh == 1) {
                if (t <= 12)      asm volatile("s_waitcnt vmcnt(8)" ::: "memory");
                else if (t == 13) asm volatile("s_waitcnt vmcnt(4)" ::: "memory");
                else if (t == 14) asm volatile("s_waitcnt vmcnt(0)" ::: "memory");
            }
            asm volatile("s_barrier" ::: "memory");
        }
    }
#undef KV_STAGE

    // ---- coalesced epilogue via LDS re-stage (ring buffers are dead) ----
    bf16* EP = &SH[0][0][0];

    if (nt < 2) {
        // K half: per row-half, stage [128 rows][256 cols] (+8 pad) then copy
        // out 512B-contiguous rows with 16B/lane stores.
#pragma unroll
        for (int half = 0; half < 2; ++half) {
            __syncthreads();
            if (wm == half) {
#pragma unroll
                for (int i = 0; i < 8; ++i)
#pragma unroll
                    for (int j = 0; j < 4; ++j) {
                        const int col = wn * 64 + j * 16 + mi;
#pragma unroll
                        for (int r = 0; r < 4; ++r)
                            EP[(i * 16 + quad * 4 + r) * 264 + col] =
                                (bf16)acc[i][j][r];
                    }
            }
            __syncthreads();
#pragma unroll
            for (int rr = 0; rr < 8; ++rr) {
                const int row_l = rr * 16 + (tid >> 5);   // 0..127
                const int c8    = (tid & 31) * 8;         // 0..248
                *(bf16x8*)&Kout[(size_t)(m0 + half * 128 + row_l) * 512 + n0 + c8] =
                    *(const bf16x8*)&EP[row_l * 264 + c8];
            }
        }
    } else {
        // V half: per batch (= wm half), stage [256 dd][128 lat] (+4 pad) then
        // copy out a contiguous 64KB panel with 16B/lane stores.
#pragma unroll
        for (int half = 0; half < 2; ++half) {
            __syncthreads();
            if (wm == half) {
#pragma unroll
                for (int i = 0; i < 8; ++i)
#pragma unroll
                    for (int j = 0; j < 4; ++j) {
                        const int dd_l = wn * 64 + j * 16 + mi;
                        const int lat0 = i * 16 + quad * 4;
                        *(bf16x4*)&EP[dd_l * 132 + lat0] =
                            bf16x4{(bf16)acc[i][j][0], (bf16)acc[i][j][1],
                                   (bf16)acc[i][j][2], (bf16)acc[i][j][3]};
                    }
            }
            __syncthreads();
            const size_t b = (size_t)mt * 2 + half;
#pragma unroll
            for (int rr = 0; rr < 8; ++rr) {
                const int dd_l = rr * 32 + (tid >> 4);    // 0..255
                const int l8   = (tid & 15) * 8;          // 0..120
                *(bf16x8*)&Vt[(b * 512 + (n0 - 512) + dd_l) * 128 + l8] =
                    *(const bf16x8*)&EP[dd_l * 132 + l8];
            }
        }
    }
}

// ---------------------------------------------------------------------------
// Attention: 4 waves/block, wave w handles bh = blockIdx.x*4 + w.
// K row-major (131072, 512); Vt transposed (1024, 512, 128): all MFMA operands
// are contiguous 16B loads. Mask-aware: only ntiles = (b%128)/16+1 tiles live.
__global__ __launch_bounds__(256) void attn_kernel(const bf16* __restrict__ Q,
                                                   const bf16* __restrict__ K,
                                                   const bf16* __restrict__ Vt,
                                                   bf16* __restrict__ O) {
    __shared__ alignas(16) bf16 Plds[4][16 * 136];   // per-wave P tile, padded

    const int w      = threadIdx.x >> 6;
    const int bh     = blockIdx.x * 4 + w;
    const int b      = bh >> 3;
    const int h      = bh & 7;
    const int rowb   = b & 127;                   // allowed latents: j <= rowb
    const int ntiles = (rowb >> 4) + 1;           // active 16-latent tiles
    const int nkt    = (ntiles + 1) >> 1;         // active 32-latent PV k-steps
    const int lane   = threadIdx.x & 63;
    const int mi     = lane & 15;
    const int quad   = lane >> 4;

    // Q fragments: A[m=tok=mi][k=quad*8+j]
    const bf16* qbase = Q + (size_t)(b * 16 + mi) * 512 + h * 64 + quad * 8;
    const bf16x8 aq0 = *(const bf16x8*)(qbase);
    const bf16x8 aq1 = *(const bf16x8*)(qbase + 32);

    // scores: B[k=dh][n=lat] from K rows (BT form)
    float4v sc[8];
    const bf16* kbase = K + (size_t)(b * 128 + mi) * 512 + h * 64 + quad * 8;
#pragma unroll
    for (int jt = 0; jt < 8; ++jt) {
        if (jt < ntiles) {
            const bf16* kb = kbase + (size_t)jt * 16 * 512;
            bf16x8 bk0 = *(const bf16x8*)(kb);
            bf16x8 bk1 = *(const bf16x8*)(kb + 32);
            float4v a = {};
            a = MFMA16(aq0, bk0, a);
            a = MFMA16(aq1, bk1, a);
            sc[jt] = a;
        }
    }

    // mask boundary tile + scale (col = jt*16 + mi)
#pragma unroll
    for (int jt = 0; jt < 8; ++jt) {
        if (jt < ntiles) {
            const bool masked = (jt * 16 + mi) > rowb;
#pragma unroll
            for (int r = 0; r < 4; ++r)
                sc[jt][r] = masked ? -1e30f : sc[jt][r] * 0.125f;
        }
    }

    // softmax per token row (row = quad*4+r), reduce across the 16 mi lanes
#pragma unroll
    for (int r = 0; r < 4; ++r) {
        float mx = sc[0][r];
#pragma unroll
        for (int jt = 1; jt < 8; ++jt)
            if (jt < ntiles) mx = fmaxf(mx, sc[jt][r]);
#pragma unroll
        for (int off = 1; off < 16; off <<= 1) mx = fmaxf(mx, __shfl_xor(mx, off, 64));
        float s = 0.f;
#pragma unroll
        for (int jt = 0; jt < 8; ++jt) {
            if (jt < ntiles) {
                float p = __expf(sc[jt][r] - mx);
                sc[jt][r] = p;
                s += p;
            }
        }
#pragma unroll
        for (int off = 1; off < 16; off <<= 1) s += __shfl_xor(s, off, 64);
        const float inv = 1.f / s;
#pragma unroll
        for (int jt = 0; jt < 8; ++jt) {
            if (jt < 2 * nkt) {
                float p = (jt < ntiles) ? sc[jt][r] * inv : 0.f;
                Plds[w][(quad * 4 + r) * 136 + jt * 16 + mi] = (bf16)p;
            }
        }
    }
    __syncthreads();

    // out = P @ V: A[m=tok][k=lat] from Plds; B[k=lat][n=dd] from Vt rows.
    float4v ao[4] = {};
    const bf16* vb0 = Vt + ((size_t)b * 512 + h * 64) * 128;
#pragma unroll
    for (int ks = 0; ks < 4; ++ks) {
        if (ks < nkt) {
            bf16x8 ap = *(const bf16x8*)&Plds[w][mi * 136 + ks * 32 + quad * 8];
#pragma unroll
            for (int jt = 0; jt < 4; ++jt) {
                bf16x8 bv = *(const bf16x8*)(vb0 + (size_t)(jt * 16 + mi) * 128
                                             + ks * 32 + quad * 8);
                ao[jt] = MFMA16(ap, bv, ao[jt]);
            }
        }
    }

    // write merged-head output (16384, 512) bf16
#pragma unroll
    for (int jt = 0; jt < 4; ++jt)
#pragma unroll
        for (int r = 0; r < 4; ++r)
            O[(size_t)(b * 16 + quad * 4 + r) * 512 + h * 64 + jt * 16 + mi] =
                (bf16)ao[jt][r];
}

// ---------------------------------------------------------------------------
extern "C" void kernel_launch(void* const* d_in, const int* in_sizes, int n_in,
                              void* d_out, int out_size, void* d_ws, size_t ws_size,
                              hipStream_t stream) {
    const float* x  = (const float*)d_in[0];   // (16384, 512)
    const float* l  = (const float*)d_in[1];   // (131072, 512)
    const float* Wq = (const float*)d_in[2];
    const float* Wk = (const float*)d_in[3];
    const float* Wv = (const float*)d_in[4];
    const float* Wo = (const float*)d_in[5];
    const float* bo = (const float*)d_in[6];
    // d_in[7] = num_heads (8), hard-coded.

    char* ws = (char*)d_ws;
    size_t off = 0;
    bf16* Wq_b  = (bf16*)(ws + off); off += (size_t)512 * 512 * 2;
    bf16* Wo_b  = (bf16*)(ws + off); off += (size_t)512 * 512 * 2;
    bf16* Wkv_b = (bf16*)(ws + off); off += (size_t)1024 * 512 * 2;   // [Wk;Wv]
    bf16* xb    = (bf16*)(ws + off); off += (size_t)16384 * 512 * 2;
    bf16* lb    = (bf16*)(ws + off); off += (size_t)131072 * 512 * 2;
    bf16* Qb    = (bf16*)(ws + off); off += (size_t)16384 * 512 * 2;
    bf16* Kb    = (bf16*)(ws + off); off += (size_t)131072 * 512 * 2;
    bf16* Vtb   = (bf16*)(ws + off); off += (size_t)1024 * 512 * 128 * 2;
    bf16* AOb   = (bf16*)(ws + off);

    cast_weights<<<1024, 256, 0, stream>>>(Wq, Wk, Wv, Wo, Wq_b, Wkv_b, Wo_b);
    cast_f32_bf16<<<2048, 256, 0, stream>>>(x, xb, 16384 * 512 / 4);
    cast_f32_bf16<<<8192, 256, 0, stream>>>(l, lb, 131072 * 512 / 4);

    // Q: 128 m-tiles x 4 n-tiles (old 128^2 structure, small shape)
    gemm_bt<0><<<512, 256, 0, stream>>>(xb, Wq_b, Qb, nullptr, 4, 16);
    // KV: 512 m-tiles x 4 n-tiles of 256^2, phased schedule
    gemm_kv<<<2048, 512, 0, stream>>>(lb, Wkv_b, Kb, Vtb);

    attn_kernel<<<2048, 256, 0, stream>>>(Qb, Kb, Vtb, AOb);

    gemm_bt<2><<<512, 256, 0, stream>>>(AOb, Wo_b, d_out, bo, 4, 16);
}